// Round 1
// baseline (89725.177 us; speedup 1.0000x reference)
//
#include <hip/hip_runtime.h>
#include <cstdint>

// Problem dims
// B=64 T=512 S=500 M=80 E=512 P=256 H=1024 A=128 F_LOC=32 K_LOC=31

// RNG_SCHEME: 0 = JAX threefry partitionable (bits = o0^o1 of enc(0, idx))  [modern JAX default]
//             1 = original scheme (half-split counter array)
//             2 = partitionable, take o0 ; 3 = partitionable, take o1
#ifndef RNG_SCHEME
#define RNG_SCHEME 0
#endif

__device__ __forceinline__ void tf2x32(uint32_t k0, uint32_t k1, uint32_t& x0, uint32_t& x1) {
  uint32_t ks2 = k0 ^ k1 ^ 0x1BD11BDAu;
  x0 += k0; x1 += k1;
#define TFR(r) { x0 += x1; x1 = (x1 << (r)) | (x1 >> (32 - (r))); x1 ^= x0; }
  TFR(13) TFR(15) TFR(26) TFR(6)
  x0 += k1; x1 += ks2 + 1u;
  TFR(17) TFR(29) TFR(16) TFR(24)
  x0 += ks2; x1 += k0 + 2u;
  TFR(13) TFR(15) TFR(26) TFR(6)
  x0 += k0; x1 += k1 + 3u;
  TFR(17) TFR(29) TFR(16) TFR(24)
  x0 += k1; x1 += ks2 + 4u;
  TFR(13) TFR(15) TFR(26) TFR(6)
  x0 += ks2; x1 += k0 + 5u;
#undef TFR
}

__device__ __forceinline__ uint32_t rng_bits(uint32_t k0, uint32_t k1, uint32_t idx, uint32_t half) {
#if RNG_SCHEME == 1
  uint32_t x0, x1;
  if (idx < half) { x0 = idx; x1 = idx + half; tf2x32(k0, k1, x0, x1); return x0; }
  else            { x0 = idx - half; x1 = idx; tf2x32(k0, k1, x0, x1); return x1; }
#else
  uint32_t x0 = 0u, x1 = idx;
  tf2x32(k0, k1, x0, x1);
#if RNG_SCHEME == 0
  return x0 ^ x1;
#elif RNG_SCHEME == 2
  return x0;
#else
  return x1;
#endif
#endif
}

__device__ __forceinline__ float rng_u01(uint32_t k0, uint32_t k1, uint32_t idx, uint32_t half) {
  uint32_t b = rng_bits(k0, k1, idx, half);
  return __uint_as_float((b >> 9) | 0x3f800000u) - 1.0f;
}

__device__ __forceinline__ float sigmf(float x) { return 1.0f / (1.0f + expf(-x)); }

// ---------------- folded dropout keys: kf[t] = threefry(key(7), [0, t]) -------------
__global__ void k_fold(uint32_t* __restrict__ kf) {
  int t = blockIdx.x * 256 + threadIdx.x;
  if (t < 1000) {
    uint32_t x0 = 0u, x1 = (uint32_t)t;
    tf2x32(0u, 7u, x0, x1);
    kf[2 * t] = x0; kf[2 * t + 1] = x1;
  }
}

// ---------------- processed_memory[b,t,a] = sum_e memory[b,t,e]*wm[a,e] ------------
__global__ __launch_bounds__(256) void k_pm(const float* __restrict__ mem,
                                            const float* __restrict__ wm,
                                            float* __restrict__ pm) {
  const int row0 = blockIdx.x * 8;  // flat (b*512+t)
  __shared__ float sm[8][512];
  const float4* src = (const float4*)(mem + (size_t)row0 * 512);
  float4* dst = (float4*)&sm[0][0];
  for (int i = threadIdx.x; i < 8 * 128; i += 256) dst[i] = src[i];
  __syncthreads();
  const int a = threadIdx.x & 127;
  const int rh = threadIdx.x >> 7;  // 0..1 -> rows rh*4..rh*4+3
  float acc[4] = {0.f, 0.f, 0.f, 0.f};
  for (int e = 0; e < 512; e += 4) {
    float4 w4 = *(const float4*)&wm[a * 512 + e];
#pragma unroll
    for (int r = 0; r < 4; r++) {
      acc[r] += sm[rh * 4 + r][e] * w4.x + sm[rh * 4 + r][e + 1] * w4.y +
                sm[rh * 4 + r][e + 2] * w4.z + sm[rh * 4 + r][e + 3] * w4.w;
    }
  }
#pragma unroll
  for (int r = 0; r < 4; r++) pm[(size_t)(row0 + rh * 4 + r) * 128 + a] = acc[r];
}

// ---------------- prenet layer1: rows r = s*64+b (s<500), 256 outputs --------------
__global__ __launch_bounds__(256) void k_prenet1(const float* __restrict__ din,
                                                 const float* __restrict__ w1,
                                                 float* __restrict__ buf) {
  const int r0 = blockIdx.x * 8;
  const int tid = threadIdx.x;
  __shared__ float xin[8][80];
  for (int i = tid; i < 640; i += 256) {
    int rr = i / 80, k = i - rr * 80;
    int r = r0 + rr;
    int s = r >> 6, b = r & 63;
    xin[rr][k] = (s == 0) ? 0.0f : din[((size_t)b * 500 + (s - 1)) * 80 + k];
  }
  __syncthreads();
  const int j = tid;
  float acc[8] = {};
  for (int k = 0; k < 80; k++) {
    float wv = w1[j * 80 + k];
#pragma unroll
    for (int i = 0; i < 8; i++) acc[i] += xin[i][k] * wv;
  }
#pragma unroll
  for (int i = 0; i < 8; i++) {
    int r = r0 + i;
    float x = fmaxf(acc[i], 0.0f);
    // key(101); full shape (501,64,256) -> size 8208384, half 4104192
    float u = rng_u01(0u, 101u, (uint32_t)(r * 256 + j), 4104192u);
    x = (u < 0.5f) ? x * 2.0f : 0.0f;
    buf[(size_t)r * 256 + j] = x;
  }
}

// ---------------- prenet layer2 (in-place) ----------------------------------------
__global__ __launch_bounds__(256) void k_prenet2(float* __restrict__ buf,
                                                 const float* __restrict__ w2) {
  const int r0 = blockIdx.x * 8;
  const int tid = threadIdx.x;
  __shared__ float xin[8][256];
  for (int i = tid; i < 2048; i += 256) xin[i >> 8][i & 255] = buf[(size_t)r0 * 256 + i];
  __syncthreads();
  const int j = tid;
  float acc[8] = {};
  for (int k = 0; k < 256; k++) {
    float wv = w2[j * 256 + k];
#pragma unroll
    for (int i = 0; i < 8; i++) acc[i] += xin[i][k] * wv;
  }
#pragma unroll
  for (int i = 0; i < 8; i++) {
    int r = r0 + i;
    float x = fmaxf(acc[i], 0.0f);
    float u = rng_u01(0u, 102u, (uint32_t)(r * 256 + j), 4104192u);
    x = (u < 0.5f) ? x * 2.0f : 0.0f;
    buf[(size_t)r * 256 + j] = x;
  }
}

// ---------------- LSTM gate GEMM, K-split partials --------------------------------
// gates[b,j] partial over k-chunk;  x = concat(s0[L0], s1[L1], sh[1024])
// w_ih covers [0, L0+L1), w_hh covers the rest. grid (4096/64, KS), 256 thr.
__global__ __launch_bounds__(256) void k_gemm_part(
    const float* __restrict__ s0, int L0,
    const float* __restrict__ s1, int L1,
    const float* __restrict__ sh,
    const float* __restrict__ wih, const float* __restrict__ whh,
    int Ktot, int chunk, float* __restrict__ part) {
  const int jbase = blockIdx.x * 64;
  const int k0 = blockIdx.y * chunk;
  const int Lih = L0 + L1;
  __shared__ float xs[32][68];
  __shared__ float wsm[32][68];
  const int tid = threadIdx.x;
  const int bq = tid & 15, jq = tid >> 4;
  float acc[4][4] = {};
  for (int kb = k0; kb < k0 + chunk; kb += 32) {
#pragma unroll
    for (int i = 0; i < 8; i++) {
      int idx = tid + i * 256;
      int r = idx >> 5, kk = idx & 31;
      int k = kb + kk;
      float xv;
      if (k < L0)       xv = s0[r * L0 + k];
      else if (k < Lih) xv = s1[r * L1 + (k - L0)];
      else              xv = sh[r * 1024 + (k - Lih)];
      xs[kk][r] = xv;
      float wv;
      int j = jbase + r;
      if (k < Lih) wv = wih[(size_t)j * Lih + k];
      else         wv = whh[(size_t)j * 1024 + (k - Lih)];
      wsm[kk][r] = wv;
    }
    __syncthreads();
#pragma unroll
    for (int kk = 0; kk < 32; kk++) {
      float4 xv = *(const float4*)&xs[kk][bq * 4];
      float4 wv = *(const float4*)&wsm[kk][jq * 4];
      acc[0][0] += wv.x * xv.x; acc[0][1] += wv.x * xv.y; acc[0][2] += wv.x * xv.z; acc[0][3] += wv.x * xv.w;
      acc[1][0] += wv.y * xv.x; acc[1][1] += wv.y * xv.y; acc[1][2] += wv.y * xv.z; acc[1][3] += wv.y * xv.w;
      acc[2][0] += wv.z * xv.x; acc[2][1] += wv.z * xv.y; acc[2][2] += wv.z * xv.z; acc[2][3] += wv.z * xv.w;
      acc[3][0] += wv.w * xv.x; acc[3][1] += wv.w * xv.y; acc[3][2] += wv.w * xv.z; acc[3][3] += wv.w * xv.w;
    }
    __syncthreads();
  }
  float* pbase = part + (size_t)(blockIdx.y * 64) * 4096;
#pragma unroll
  for (int bb = 0; bb < 4; bb++) {
    int b = bq * 4 + bb;
    float4 o = make_float4(acc[0][bb], acc[1][bb], acc[2][bb], acc[3][bb]);
    *(float4*)&pbase[(size_t)b * 4096 + jbase + jq * 4] = o;
  }
}

// ---------------- attn LSTM pointwise + dropout + q = ah @ Wq^T -------------------
__global__ __launch_bounds__(256) void k_attn_point(
    const float* __restrict__ part,
    const float* __restrict__ bih, const float* __restrict__ bhh,
    float* __restrict__ ac, float* __restrict__ ah,
    const uint32_t* __restrict__ kf, int dsel,
    const float* __restrict__ wq, float* __restrict__ q) {
  const int b = blockIdx.x, tid = threadIdx.x;
  __shared__ float ahs[1024];
  __shared__ float qred[256];
  const uint32_t fk0 = kf[2 * dsel], fk1 = kf[2 * dsel + 1];
#pragma unroll
  for (int hq = 0; hq < 4; hq++) {
    int h = tid + hq * 256;
    float gi = bih[h] + bhh[h];
    float gf = bih[h + 1024] + bhh[h + 1024];
    float gg = bih[h + 2048] + bhh[h + 2048];
    float go = bih[h + 3072] + bhh[h + 3072];
    for (int ks = 0; ks < 8; ks++) {
      const float* p = part + (size_t)(ks * 64 + b) * 4096;
      gi += p[h]; gf += p[h + 1024]; gg += p[h + 2048]; go += p[h + 3072];
    }
    float c = sigmf(gf) * ac[b * 1024 + h] + sigmf(gi) * tanhf(gg);
    float hn = sigmf(go) * tanhf(c);
    ac[b * 1024 + h] = c;
    float u = rng_u01(fk0, fk1, (uint32_t)(b * 1024 + h), 32768u);
    hn = (u < 0.9f) ? hn / 0.9f : 0.0f;
    ah[b * 1024 + h] = hn;
    ahs[h] = hn;
  }
  __syncthreads();
  {
    int a = tid & 127, half = tid >> 7;
    const float* wr = wq + (size_t)a * 1024 + half * 512;
    const float* hs = ahs + half * 512;
    float a0 = 0, a1 = 0, a2 = 0, a3 = 0;
    for (int h2 = 0; h2 < 512; h2 += 4) {
      a0 += hs[h2] * wr[h2]; a1 += hs[h2 + 1] * wr[h2 + 1];
      a2 += hs[h2 + 2] * wr[h2 + 2]; a3 += hs[h2 + 3] * wr[h2 + 3];
    }
    qred[tid] = (a0 + a1) + (a2 + a3);
  }
  __syncthreads();
  if (tid < 128) q[b * 128 + tid] = qred[tid] + qred[tid + 128];
}

// ---------------- energies: loc-conv + loc-dense + tanh + dot v + mask ------------
// grid (B, T/64), 256 thr: t = tid&63, aq = tid>>6 splits f and a ranges
__global__ __launch_bounds__(256) void k_energy(
    const float* __restrict__ aw, const float* __restrict__ awc,
    const float* __restrict__ q, const float* __restrict__ pm,
    const float* __restrict__ wconv, const float* __restrict__ wld,
    const float* __restrict__ v, const int* __restrict__ mlen,
    float* __restrict__ energ) {
  const int b = blockIdx.x;
  const int t0 = blockIdx.y * 64;
  const int tid = threadIdx.x;
  const int t = tid & 63, aq = tid >> 6;
  __shared__ float sa[2][96];
  __shared__ float sq[128], sv[128];
  __shared__ float sw[1984];
  __shared__ float sld[128][32];
  __shared__ float sloc[64][33];
  __shared__ float spart[64][4];
  for (int i = tid; i < 94; i += 256) {
    int tt = t0 - 15 + i;
    bool ok = (tt >= 0 && tt < 512);
    sa[0][i] = ok ? aw[b * 512 + tt] : 0.0f;
    sa[1][i] = ok ? awc[b * 512 + tt] : 0.0f;
  }
  if (tid < 128) { sq[tid] = q[b * 128 + tid]; sv[tid] = v[tid]; }
  for (int i = tid; i < 1984; i += 256) sw[i] = wconv[i];
  for (int i = tid; i < 4096; i += 256) ((float*)sld)[i] = wld[i];
  __syncthreads();
  const int len = mlen[b];
  const int tt = t0 + t;
  const bool act = (tt < len);
  if (act) {
    for (int f = aq * 8; f < aq * 8 + 8; f++) {
      const float* w0 = sw + f * 62;
      const float* w1 = w0 + 31;
      float a = 0;
#pragma unroll
      for (int k = 0; k < 31; k++) a += sa[0][t + k] * w0[k] + sa[1][t + k] * w1[k];
      sloc[t][f] = a;
    }
  }
  __syncthreads();
  if (act) {
    const float* pmr = pm + (size_t)(b * 512 + tt) * 128;
    float acc = 0;
    for (int a = aq * 32; a < aq * 32 + 32; a++) {
      float pl = 0;
#pragma unroll
      for (int f = 0; f < 32; f++) pl += sloc[t][f] * sld[a][f];
      float x = sq[a] + pl + pmr[a];
      float ex = __expf(2.0f * x);
      acc += sv[a] * (1.0f - 2.0f / (ex + 1.0f));
    }
    spart[t][aq] = acc;
  }
  __syncthreads();
  if (tid < 64) {
    int g = t0 + tid;
    float e = (g < len) ? (spart[tid][0] + spart[tid][1]) + (spart[tid][2] + spart[tid][3]) : -1e9f;
    energ[b * 512 + g] = e;
  }
}

// ---------------- softmax + alignment out + awc accum + ctx = aw @ memory ---------
__global__ __launch_bounds__(256) void k_softmax_ctx(
    const float* __restrict__ energ, const int* __restrict__ mlen,
    const float* __restrict__ memv,
    float* __restrict__ aw, float* __restrict__ awc, float* __restrict__ ctx,
    float* __restrict__ out_align, int s) {
  const int b = blockIdx.x, tid = threadIdx.x;
  __shared__ float se[512];
  __shared__ float redm[4], reds[4];
  const int len = mlen[b];
  float e0 = energ[b * 512 + tid];
  float e1 = energ[b * 512 + 256 + tid];
  float m = fmaxf(e0, e1);
  for (int off = 32; off > 0; off >>= 1) m = fmaxf(m, __shfl_down(m, off));
  if ((tid & 63) == 0) redm[tid >> 6] = m;
  __syncthreads();
  const float maxv = fmaxf(fmaxf(redm[0], redm[1]), fmaxf(redm[2], redm[3]));
  float x0 = (tid < len) ? __expf(e0 - maxv) : 0.0f;
  float x1 = (tid + 256 < len) ? __expf(e1 - maxv) : 0.0f;
  float sm = x0 + x1;
  for (int off = 32; off > 0; off >>= 1) sm += __shfl_down(sm, off);
  if ((tid & 63) == 0) reds[tid >> 6] = sm;
  __syncthreads();
  const float tot = (reds[0] + reds[1]) + (reds[2] + reds[3]);
  float a0 = x0 / tot, a1 = x1 / tot;
  aw[b * 512 + tid] = a0; aw[b * 512 + 256 + tid] = a1;
  awc[b * 512 + tid] += a0; awc[b * 512 + 256 + tid] += a1;
  float* oa = out_align + (size_t)b * (500 * 512) + (size_t)s * 512;
  oa[tid] = a0; oa[tid + 256] = a1;
  se[tid] = a0; se[tid + 256] = a1;
  __syncthreads();
  const float* mb = memv + (size_t)b * (512 * 512);
  float c0 = 0, c1 = 0;
  for (int tt = 0; tt < len; tt++) {
    float w = se[tt];
    c0 += w * mb[(size_t)tt * 512 + tid];
    c1 += w * mb[(size_t)tt * 512 + 256 + tid];
  }
  ctx[b * 512 + tid] = c0;
  ctx[b * 512 + 256 + tid] = c1;
}

// ---------------- dec LSTM pointwise + dropout + mel/gate outputs -----------------
__global__ __launch_bounds__(256) void k_dec_out(
    const float* __restrict__ part,
    const float* __restrict__ bih, const float* __restrict__ bhh,
    float* __restrict__ dc, float* __restrict__ dh,
    const uint32_t* __restrict__ kf, int dsel,
    const float* __restrict__ ctx,
    const float* __restrict__ projw, const float* __restrict__ projb,
    const float* __restrict__ gatew, const float* __restrict__ gateb,
    float* __restrict__ out_mel, float* __restrict__ out_gate, int s) {
  const int b = blockIdx.x, tid = threadIdx.x;
  __shared__ float hc[1536];
  __shared__ float ored[256];
  const uint32_t fk0 = kf[2 * dsel], fk1 = kf[2 * dsel + 1];
#pragma unroll
  for (int hq = 0; hq < 4; hq++) {
    int h = tid + hq * 256;
    float gi = bih[h] + bhh[h];
    float gf = bih[h + 1024] + bhh[h + 1024];
    float gg = bih[h + 2048] + bhh[h + 2048];
    float go = bih[h + 3072] + bhh[h + 3072];
    for (int ks = 0; ks < 8; ks++) {
      const float* p = part + (size_t)(ks * 64 + b) * 4096;
      gi += p[h]; gf += p[h + 1024]; gg += p[h + 2048]; go += p[h + 3072];
    }
    float c = sigmf(gf) * dc[b * 1024 + h] + sigmf(gi) * tanhf(gg);
    float hn = sigmf(go) * tanhf(c);
    dc[b * 1024 + h] = c;
    float u = rng_u01(fk0, fk1, (uint32_t)(b * 1024 + h), 32768u);
    hn = (u < 0.9f) ? hn / 0.9f : 0.0f;
    dh[b * 1024 + h] = hn;
    hc[h] = hn;
  }
  for (int i = tid; i < 512; i += 256) hc[1024 + i] = ctx[b * 512 + i];
  __syncthreads();
  {
    int mm = tid & 127, half = tid >> 7;
    float s4 = 0;
    if (mm <= 80) {
      const float* wr = ((mm < 80) ? (projw + (size_t)mm * 1536) : gatew) + half * 768;
      const float* hs = hc + half * 768;
      float a0 = 0, a1 = 0, a2 = 0, a3 = 0;
      for (int k2 = 0; k2 < 768; k2 += 4) {
        a0 += hs[k2] * wr[k2]; a1 += hs[k2 + 1] * wr[k2 + 1];
        a2 += hs[k2 + 2] * wr[k2 + 2]; a3 += hs[k2 + 3] * wr[k2 + 3];
      }
      s4 = (a0 + a1) + (a2 + a3);
    }
    ored[tid] = s4;
  }
  __syncthreads();
  if (tid <= 80) {
    float tot = ored[tid] + ored[tid + 128];
    if (tid < 80) out_mel[(size_t)b * 40000 + (size_t)s * 80 + tid] = tot + projb[tid];
    else          out_gate[b * 500 + s] = tot + gateb[0];
  }
}

extern "C" void kernel_launch(void* const* d_in, const int* in_sizes, int n_in,
                              void* d_out, int out_size, void* d_ws, size_t ws_size,
                              hipStream_t stream) {
  const float* memory = (const float*)d_in[0];
  const int*   mlen   = (const int*)d_in[1];
  const float* dec_in = (const float*)d_in[2];
  const float* pw1    = (const float*)d_in[3];
  const float* pw2    = (const float*)d_in[4];
  const float* awih   = (const float*)d_in[5];
  const float* awhh   = (const float*)d_in[6];
  const float* abih   = (const float*)d_in[7];
  const float* abhh   = (const float*)d_in[8];
  const float* dwih   = (const float*)d_in[9];
  const float* dwhh   = (const float*)d_in[10];
  const float* dbih   = (const float*)d_in[11];
  const float* dbhh   = (const float*)d_in[12];
  const float* wq     = (const float*)d_in[13];
  const float* wm     = (const float*)d_in[14];
  const float* av     = (const float*)d_in[15];
  const float* wconv  = (const float*)d_in[16];
  const float* wld    = (const float*)d_in[17];
  const float* projw  = (const float*)d_in[18];
  const float* projb  = (const float*)d_in[19];
  const float* gatew  = (const float*)d_in[20];
  const float* gateb  = (const float*)d_in[21];

  float* out       = (float*)d_out;
  float* out_mel   = out;                 // B*S*M = 2,560,000
  float* out_gate  = out + 2560000;       // B*S   = 32,000
  float* out_align = out + 2592000;       // B*S*T = 16,384,000

  float* ws     = (float*)d_ws;
  float* pm     = ws;                      // 4,194,304
  float* prenet = pm + 4194304;            // 8,192,000 (layer1 then in-place layer2)
  float* part   = prenet + 8192000;        // 8*64*4096 = 2,097,152
  float* st     = part + 2097152;          // states (memset 0):
  float* ah  = st;                         // 65536
  float* ac  = ah + 65536;
  float* dh  = ac + 65536;
  float* dc  = dh + 65536;
  float* aw  = dc + 65536;                 // 32768
  float* awc = aw + 32768;
  float* ctx = awc + 32768;                // 32768
  float* q     = ctx + 32768;              // 8192
  float* energ = q + 8192;                 // 32768
  uint32_t* kf = (uint32_t*)(energ + 32768);  // 2000 u32

  hipMemsetAsync(st, 0, (size_t)(4 * 65536 + 3 * 32768) * sizeof(float), stream);
  k_fold<<<4, 256, 0, stream>>>(kf);
  k_pm<<<4096, 256, 0, stream>>>(memory, wm, pm);
  k_prenet1<<<4000, 256, 0, stream>>>(dec_in, pw1, prenet);
  k_prenet2<<<4000, 256, 0, stream>>>(prenet, pw2);

  for (int s = 0; s < 500; s++) {
    // attention LSTM: x = [prenet_xt(256) | ctx(512)], h = ah ; K = 1792
    k_gemm_part<<<dim3(64, 8), 256, 0, stream>>>(prenet + (size_t)s * 16384, 256,
                                                 ctx, 512, ah, awih, awhh, 1792, 224, part);
    k_attn_point<<<64, 256, 0, stream>>>(part, abih, abhh, ac, ah, kf, 2 * s, wq, q);
    k_energy<<<dim3(64, 8), 256, 0, stream>>>(aw, awc, q, pm, wconv, wld, av, mlen, energ);
    k_softmax_ctx<<<64, 256, 0, stream>>>(energ, mlen, memory, aw, awc, ctx, out_align, s);
    // decoder LSTM: x = [ah(1024) | ctx(512)], h = dh ; K = 2560
    k_gemm_part<<<dim3(64, 8), 256, 0, stream>>>(ah, 1024, ctx, 512, dh,
                                                 dwih, dwhh, 2560, 320, part);
    k_dec_out<<<64, 256, 0, stream>>>(part, dbih, dbhh, dc, dh, kf, 2 * s + 1, ctx,
                                      projw, projb, gatew, gateb, out_mel, out_gate, s);
  }
}